// Round 4
// baseline (216.451 us; speedup 1.0000x reference)
//
#include <hip/hip_runtime.h>

#define RING_B (16*6144)                 // 16 row-slots x 6 cols x 1KB bf16 = 96KB

typedef __attribute__((ext_vector_type(8))) short bf16x8;
typedef __attribute__((ext_vector_type(4))) float f32x4;
typedef __attribute__((ext_vector_type(4))) unsigned int u32x4;

__device__ __forceinline__ short f2bf(float f) {
  union { float f; unsigned u; } v; v.f = f;
  unsigned r = v.u + 0x7FFFu + ((v.u >> 16) & 1u);   // RNE
  return (short)(r >> 16);
}

__device__ __forceinline__ void gld_lds16(const void* g, void* l) {
  __builtin_amdgcn_global_load_lds(
      (__attribute__((address_space(1))) void*)(g),
      (__attribute__((address_space(3))) void*)(l), 16, 0, 0);
}

// ---- Pass 1: permute channels -> grouped bf16, bake (row,col) XOR swizzle ----
// (unchanged from round 3; ~40us, XCD-matched with conv consumer)
__global__ __launch_bounds__(256) void permute_kernel(
    const float* __restrict__ x, const int* __restrict__ bin,
    unsigned char* __restrict__ xs)
{
  __shared__ unsigned short pos_tab[512];
  __shared__ char stage[4][2][1024];
  const int t = threadIdx.x;
  { int cA = bin[t], cB = bin[t + 256];
    pos_tab[cA] = (unsigned short)t;
    pos_tab[cB] = (unsigned short)(t + 256); }
  __syncthreads();

  const int w = t >> 6, lane = t & 63;
  const int q = blockIdx.x;
  const int i = q & 255, sub = q >> 8;
  const int b = i >> 4, strip = i & 15;
  const int cb = lane * 4;

#pragma unroll 2
  for (int k = 0; k < 8; ++k) {
    const int idx = w * 8 + k;
    const int r  = sub * 8 + (idx >> 2);
    const int gc = strip * 4 + (idx & 3);
    const int p  = (b * 64 + r) * 64 + gc;
    const unsigned swz = ((unsigned)((r & 3) | ((gc & 1) << 2))) << 4;
    const float* src = x + (size_t)p * 512 + cb;
    f32x4 v0 = *(const f32x4*)src;
    f32x4 v1 = *(const f32x4*)(src + 256);
    char* st = stage[w][k & 1];
#pragma unroll
    for (int j = 0; j < 4; ++j)
      *(short*)(st + ((pos_tab[cb + j] * 2u) ^ swz)) = f2bf(v0[j]);
#pragma unroll
    for (int j = 0; j < 4; ++j)
      *(short*)(st + ((pos_tab[256 + cb + j] * 2u) ^ swz)) = f2bf(v1[j]);
    asm volatile("s_waitcnt lgkmcnt(0)");
    u32x4 d = *(const u32x4*)(st + lane * 16);
    *(u32x4*)(xs + (size_t)p * 1024 + lane * 16) = d;
  }
}

// ---- Pass 2: conv, 4x4 patches, 16-slot ring, DIRECT scattered stores,
//      ONE counted-vmcnt barrier per 4-row iteration ----
__global__ __launch_bounds__(1024, 4) void conv_kernel(
    const unsigned char* __restrict__ xs, const float* __restrict__ wts,
    const float* __restrict__ bias, const int* __restrict__ bout,
    float* __restrict__ out)
{
  extern __shared__ char smem[];

  const int t = threadIdx.x, lane = t & 63, g = t >> 6;
  const int g4 = lane >> 4, n16 = lane & 15;
  const int bid = blockIdx.x;            // 256 = b*16 + strip
  const int b = bid >> 4, strip = bid & 15;
  const int w0 = strip * 4;
  const int gbase = g * 64 + g4 * 16;

  u32x4 z4 = {0, 0, 0, 0};
  for (int zz = t * 16; zz < RING_B; zz += 16384)
    *(u32x4*)(smem + zz) = z4;           // zeros cover all halos (rows -1/64, cols -1/64)

  // weight fragments: B elem j <-> ci = g4*8+j (same kappa as A)
  bf16x8 wf[9][2];
  {
    const float* Wg = wts + g * 9216;
#pragma unroll
    for (int tap = 0; tap < 9; ++tap)
#pragma unroll
      for (int nt = 0; nt < 2; ++nt) {
        bf16x8 f;
#pragma unroll
        for (int j = 0; j < 8; ++j)
          f[j] = f2bf(Wg[(tap * 32 + g4 * 8 + j) * 32 + nt * 16 + n16]);
        wf[tap][nt] = f;
      }
  }
  const int opos0 = bout[g * 32 + n16];
  const int opos1 = bout[g * 32 + 16 + n16];
  const float bb0 = bias[opos0];
  const float bb1 = bias[opos1];

  // per-lane output base: pixel (row b*64 + g4 + h, col w0 + rr), channel opos
  float* outp = out + ((size_t)(b * 64 + g4) * 64 + w0) * 512;

  // DMA assignment: d = g and g+16 over (row r = d/6, col c = d%6)
  const int r0 = g / 6,        c0 = g - r0 * 6;
  const int r1 = (g + 16) / 6, c1 = (g + 16) - r1 * 6;
  const int gc0 = w0 - 1 + c0, gc1 = w0 - 1 + c1;
  const bool cv0 = (gc0 >= 0 && gc0 <= 63);
  const bool cv1 = (gc1 >= 0 && gc1 <= 63);
  const unsigned char* xb = xs + (size_t)(b * 64) * 64 * 1024;

  __syncthreads();                       // zeros visible before DMA
  // prologue: stage rows 0..4 (30 DMAs)
  if (cv0) gld_lds16(xb + (size_t)(r0 * 64 + gc0) * 1024 + lane * 16,
                     smem + r0 * 6144 + c0 * 1024);
  if (g < 14 && cv1) gld_lds16(xb + (size_t)(r1 * 64 + gc1) * 1024 + lane * 16,
                               smem + r1 * 6144 + c1 * 1024);
  asm volatile("s_waitcnt vmcnt(0)\ns_barrier" ::: "memory");

  for (int h = 0; h < 64; h += 4) {
    // P0: prefetch rows h+5..h+8 (slots disjoint from live h-1..h+4)
    {
      int gr0 = h + 5 + r0;
      if (gr0 <= 63 && cv0)
        gld_lds16(xb + (size_t)(gr0 * 64 + gc0) * 1024 + lane * 16,
                  smem + (gr0 & 15) * 6144 + c0 * 1024);
      int gr1 = h + 5 + r1;
      if (g < 8 && gr1 <= 63 && cv1)
        gld_lds16(xb + (size_t)(gr1 * 64 + gc1) * 1024 + lane * 16,
                  smem + (gr1 & 15) * 6144 + c1 * 1024);
      if (h == 52 && t < 384) *(u32x4*)(smem + t * 16) = z4;  // slot 0 <- zeros (row 64)
    }
    asm volatile("" ::: "memory");       // pin DMA issue early

    // P1: MFMA, 9 taps; A = one swizzled ds_read_b128 (pixel m=(n16>>2, n16&3))
    f32x4 a0 = {0, 0, 0, 0}, a1 = {0, 0, 0, 0};
#pragma unroll
    for (int dh = 0; dh < 3; ++dh) {
      int gr = h + (n16 >> 2) + dh - 1;
      int rowbase = (gr & 15) * 6144;
      int rsw = (gr & 3) << 4;
#pragma unroll
      for (int dw = 0; dw < 3; ++dw) {
        int cs = (n16 & 3) + dw;                     // col slot 0..5
        int csw = ((w0 - 1 + cs) & 1) << 6;
        const char* ap = smem + rowbase + cs * 1024 + (gbase ^ rsw ^ csw);
        bf16x8 a = *(const bf16x8*)ap;
        a0 = __builtin_amdgcn_mfma_f32_16x16x32_bf16(a, wf[dh * 3 + dw][0], a0, 0, 0, 0);
        a1 = __builtin_amdgcn_mfma_f32_16x16x32_bf16(a, wf[dh * 3 + dw][1], a1, 0, 0, 0);
      }
    }

    // P2: direct scattered stores with fused bias+ReLU
    // lane holds D for pixels (row h+g4, col w0+rr), couts opos0/opos1
    {
      float* op = outp + (size_t)h * (64 * 512);
#pragma unroll
      for (int rr = 0; rr < 4; ++rr) {
        op[rr * 512 + opos0] = fmaxf(a0[rr] + bb0, 0.f);
        op[rr * 512 + opos1] = fmaxf(a1[rr] + bb1, 0.f);
      }
    }
    // one barrier per iter: vmcnt(8) waits this iter's DMAs (older than the
    // 8 newest stores); store-acks drain under the next iteration
    asm volatile("s_waitcnt vmcnt(8) lgkmcnt(0)\ns_barrier" ::: "memory");
  }
}

extern "C" void kernel_launch(void* const* d_in, const int* in_sizes, int n_in,
                              void* d_out, int out_size, void* d_ws, size_t ws_size,
                              hipStream_t stream) {
  const float* x    = (const float*)d_in[0];
  const float* wts  = (const float*)d_in[1];
  const float* bias = (const float*)d_in[2];
  const int*   bin  = (const int*)d_in[3];
  const int*   bout = (const int*)d_in[4];
  float* out = (float*)d_out;
  unsigned char* xs = (unsigned char*)d_ws;   // 64 MiB
  (void)in_sizes; (void)n_in; (void)out_size; (void)ws_size;

  permute_kernel<<<dim3(2048), dim3(256), 0, stream>>>(x, bin, xs);
  conv_kernel<<<dim3(256), dim3(1024), RING_B, stream>>>(xs, wts, bias, bout, out);
}

// Round 5
// 143.852 us; speedup vs baseline: 1.5047x; 1.5047x over previous
//
#include <hip/hip_runtime.h>

#define SLOT_B 18432                    // 18 cols x 1KB (512 bf16 grouped, swizzled)
#define RING_B (4*SLOT_B)               // 73728
#define OROW_OFF RING_B
#define SMEM_T (RING_B + 2*16*512*4)    // + double-buffered fp32 orow = 139264

typedef __attribute__((ext_vector_type(8))) short bf16x8;
typedef __attribute__((ext_vector_type(4))) float f32x4;

__device__ __forceinline__ short f2bf(float f) {
  union { float f; unsigned u; } v; v.f = f;
  unsigned r = v.u + 0x7FFFu + ((v.u >> 16) & 1u);   // RNE
  return (short)(r >> 16);
}

__global__ __launch_bounds__(1024) void bconv_kernel(
    const float* __restrict__ x, const float* __restrict__ wts,
    const float* __restrict__ bias, const int* __restrict__ bin,
    const int* __restrict__ bout, float* __restrict__ out)
{
  extern __shared__ char smem[];
  float* orow = (float*)(smem + OROW_OFF);

  const int t = threadIdx.x, lane = t & 63, g = t >> 6;
  const int g4 = lane >> 4, n16 = lane & 15;
  const int bid = blockIdx.x;                 // 256 = ((b*4+strip)*4+seg)
  const int b = bid >> 4, strip = (bid >> 2) & 3, seg = bid & 3;
  const int hs = seg * 16, w0 = strip * 16;
  const int gbase = g * 64 + g4 * 16;

  // ---- inverse input-permutation, cached per lane (channels lane*8..+7) ----
  unsigned short* pos_tab = (unsigned short*)(smem + OROW_OFF);  // transient, orow region
  if (t < 512) pos_tab[bin[t]] = (unsigned short)t;
  __syncthreads();
  unsigned short inv8[8];
#pragma unroll
  for (int j = 0; j < 8; ++j) inv8[j] = pos_tab[lane * 8 + j];

  // ---- weight fragments (B elem j <-> ci = g4*8+j, kappa-consistent with A) ----
  bf16x8 wf[9][2];
  {
    const float* Wg = wts + g * 9216;
#pragma unroll
    for (int tap = 0; tap < 9; ++tap)
#pragma unroll
      for (int nt = 0; nt < 2; ++nt) {
        bf16x8 f;
#pragma unroll
        for (int j = 0; j < 8; ++j)
          f[j] = f2bf(Wg[(tap * 32 + g4 * 8 + j) * 32 + nt * 16 + n16]);
        wf[tap][nt] = f;
      }
  }
  const int opos0 = bout[g * 32 + n16];
  const int opos1 = bout[g * 32 + 16 + n16];
  const f32x4 bias0 = *(const f32x4*)(bias + lane * 8);
  const f32x4 bias1 = *(const f32x4*)(bias + lane * 8 + 4);
  const size_t xrowstride = 64 * 512;

  // staging geometry: wave g stages ring-col g (+ col g+16 for g<2)
  const int gcolA = w0 - 1 + g;
  const int gcolB = w0 - 1 + g + 16;
  const bool cvA = (gcolA >= 0);               // gcolA <= 62 always
  const bool cvB = (g < 2) && (gcolB <= 63);
  const unsigned swzA = (unsigned)((g & 7) << 4);
  const unsigned swzB = (unsigned)(((g + 16) & 7) << 4);

  // ---- prologue: stage rows hs-1, hs, hs+1 (zero-fill OOB via same path) ----
  for (int task = g; task < 54; task += 16) {
    const int r = task / 18, cs = task - r * 18;
    const int grow = hs - 1 + r, gcol = w0 - 1 + cs;
    f32x4 v0 = {0, 0, 0, 0}, v1 = {0, 0, 0, 0};
    if (grow >= 0 && gcol >= 0 && gcol <= 63) {
      const float* src = x + ((size_t)(b * 64 + grow) * 64 + gcol) * 512 + lane * 8;
      v0 = *(const f32x4*)src;
      v1 = *(const f32x4*)(src + 4);
    }
    char* sl = smem + (grow & 3) * SLOT_B + cs * 1024;
    const unsigned swz = (unsigned)((cs & 7) << 4);
#pragma unroll
    for (int j = 0; j < 4; ++j) {
      *(short*)(sl + ((inv8[j] * 2u) ^ swz))     = f2bf(v0[j]);
      *(short*)(sl + ((inv8[4 + j] * 2u) ^ swz)) = f2bf(v1[j]);
    }
  }
  asm volatile("s_waitcnt lgkmcnt(0)\ns_barrier" ::: "memory");

  for (int h = hs; h < hs + 16; ++h) {
    // A) issue stage loads for row h+2 (coalesced; latency hides under MFMA)
    const int grow = h + 2;
    const bool stg = (h <= hs + 14);
    f32x4 sA0 = {0, 0, 0, 0}, sA1 = {0, 0, 0, 0};
    f32x4 sB0 = {0, 0, 0, 0}, sB1 = {0, 0, 0, 0};
    const bool realA = stg && cvA && grow <= 63;
    const bool realB = stg && cvB && grow <= 63;
    if (realA) {
      const float* src = x + ((size_t)(b * 64 + grow) * 64 + gcolA) * 512 + lane * 8;
      sA0 = *(const f32x4*)src; sA1 = *(const f32x4*)(src + 4);
    }
    if (realB) {
      const float* src = x + ((size_t)(b * 64 + grow) * 64 + gcolB) * 512 + lane * 8;
      sB0 = *(const f32x4*)src; sB1 = *(const f32x4*)(src + 4);
    }

    // B) flush row h-1 (reads prev orow buffer; stores drain under MFMA)
    if (h > hs) {
      const float* ob = orow + ((h - 1) & 1) * 8192 + g * 512 + lane * 8;
      f32x4 y0 = *(const f32x4*)ob;
      f32x4 y1 = *(const f32x4*)(ob + 4);
      f32x4 o0, o1;
      o0[0] = fmaxf(y0[0] + bias0[0], 0.f); o0[1] = fmaxf(y0[1] + bias0[1], 0.f);
      o0[2] = fmaxf(y0[2] + bias0[2], 0.f); o0[3] = fmaxf(y0[3] + bias0[3], 0.f);
      o1[0] = fmaxf(y1[0] + bias1[0], 0.f); o1[1] = fmaxf(y1[1] + bias1[1], 0.f);
      o1[2] = fmaxf(y1[2] + bias1[2], 0.f); o1[3] = fmaxf(y1[3] + bias1[3], 0.f);
      float* dst = out + ((size_t)(b * 64 + (h - 1)) * 64 + w0 + g) * 512 + lane * 8;
      *(f32x4*)dst = o0;
      *(f32x4*)(dst + 4) = o1;
    }

    // C) MFMA: 9 taps, A = one swizzled ds_read_b128 (pixel m = n16)
    f32x4 a0 = {0, 0, 0, 0}, a1 = {0, 0, 0, 0};
#pragma unroll
    for (int dh = 0; dh < 3; ++dh) {
      const char* sb = smem + ((h - 1 + dh) & 3) * SLOT_B;
#pragma unroll
      for (int dw = 0; dw < 3; ++dw) {
        const int cs = n16 + dw;
        const char* ap = sb + cs * 1024 + (gbase ^ ((cs & 7) << 4));
        bf16x8 a = *(const bf16x8*)ap;
        a0 = __builtin_amdgcn_mfma_f32_16x16x32_bf16(a, wf[dh * 3 + dw][0], a0, 0, 0, 0);
        a1 = __builtin_amdgcn_mfma_f32_16x16x32_bf16(a, wf[dh * 3 + dw][1], a1, 0, 0, 0);
      }
    }

    // D) stage writes: convert + permute-scatter into ring slot (h+2)&3
    if (stg) {
      char* slA = smem + (grow & 3) * SLOT_B + g * 1024;
#pragma unroll
      for (int j = 0; j < 4; ++j) {
        *(short*)(slA + ((inv8[j] * 2u) ^ swzA))     = f2bf(sA0[j]);
        *(short*)(slA + ((inv8[4 + j] * 2u) ^ swzA)) = f2bf(sA1[j]);
      }
      if (g < 2) {
        char* slB = smem + (grow & 3) * SLOT_B + (g + 16) * 1024;
#pragma unroll
        for (int j = 0; j < 4; ++j) {
          *(short*)(slB + ((inv8[j] * 2u) ^ swzB))     = f2bf(sB0[j]);
          *(short*)(slB + ((inv8[4 + j] * 2u) ^ swzB)) = f2bf(sB1[j]);
        }
      }
    }

    // E) scatter D into this row's orow buffer (m = g4*4+rr = pixel col)
    {
      float* ob = orow + (h & 1) * 8192;
#pragma unroll
      for (int rr = 0; rr < 4; ++rr) {
        const int m = (g4 * 4 + rr) * 512;
        ob[m + opos0] = a0[rr];
        ob[m + opos1] = a1[rr];
      }
    }
    // single barrier: LDS-only drain (stores intentionally NOT waited)
    asm volatile("s_waitcnt lgkmcnt(0)\ns_barrier" ::: "memory");
  }

  // epilogue: flush last row
  {
    const int h1 = hs + 15;
    const float* ob = orow + (h1 & 1) * 8192 + g * 512 + lane * 8;
    f32x4 y0 = *(const f32x4*)ob;
    f32x4 y1 = *(const f32x4*)(ob + 4);
    f32x4 o0, o1;
    o0[0] = fmaxf(y0[0] + bias0[0], 0.f); o0[1] = fmaxf(y0[1] + bias0[1], 0.f);
    o0[2] = fmaxf(y0[2] + bias0[2], 0.f); o0[3] = fmaxf(y0[3] + bias0[3], 0.f);
    o1[0] = fmaxf(y1[0] + bias1[0], 0.f); o1[1] = fmaxf(y1[1] + bias1[1], 0.f);
    o1[2] = fmaxf(y1[2] + bias1[2], 0.f); o1[3] = fmaxf(y1[3] + bias1[3], 0.f);
    float* dst = out + ((size_t)(b * 64 + h1) * 64 + w0 + g) * 512 + lane * 8;
    *(f32x4*)dst = o0;
    *(f32x4*)(dst + 4) = o1;
  }
}

extern "C" void kernel_launch(void* const* d_in, const int* in_sizes, int n_in,
                              void* d_out, int out_size, void* d_ws, size_t ws_size,
                              hipStream_t stream) {
  const float* x    = (const float*)d_in[0];
  const float* wts  = (const float*)d_in[1];
  const float* bias = (const float*)d_in[2];
  const int*   bin  = (const int*)d_in[3];
  const int*   bout = (const int*)d_in[4];
  float* out = (float*)d_out;
  (void)in_sizes; (void)n_in; (void)out_size; (void)d_ws; (void)ws_size;

  bconv_kernel<<<dim3(256), dim3(1024), SMEM_T, stream>>>(x, wts, bias, bin, bout, out);
}